// Round 12
// baseline (47.140 us; speedup 1.0000x reference)
//
#include <hip/hip_runtime.h>
#include <hip/hip_bf16.h>
#include <math.h>

#define BB 8
#define NN 2048
#define HH 768
#define D1 128
#define D2 64
#define BN (BB*NN)            // 16384 rows total
#define NCH 32                // split-n chunks for S1 partial reduction (64 rows each)
#define ROWS_PER_CH (NN/NCH)  // 64

// workspace offsets (floats)
#define OFF_XNB   0u          // bf16 [BN][128]
#define OFF_XNBT  1048576u    // bf16 [8][128][2048]
#define OFF_NRM   2097152u    // f32  [BN]
#define OFF_W2    2113536u    // f32  [BN]   (h1 . c2_lw per row)
#define OFF_T2V   2129920u    // f32  [BN]   (h1 . r2 per row)
#define OFF_P1    2146304u    // bf16 [8][32][128][128] = 8 MB
#define OFF_M1T   4243456u    // bf16 [8][64][128]
#define OFF_M2F   4280320u    // f32 [8][128]

typedef __attribute__((ext_vector_type(8))) short short8v;
typedef __attribute__((ext_vector_type(4))) float f32x4;
typedef unsigned short USH;

__device__ __forceinline__ USH f2bf(float f) {
  unsigned int u = __builtin_bit_cast(unsigned int, f);
  u = (u + 0x7fffu + ((u >> 16) & 1u)) >> 16;
  return (USH)u;
}
__device__ __forceinline__ float bf2f(USH u) {
  return __builtin_bit_cast(float, ((unsigned int)u) << 16);
}
__device__ __forceinline__ short8v cvt8(float4 a, float4 b) {
  short8v v;
  v[0] = (short)f2bf(a.x); v[1] = (short)f2bf(a.y);
  v[2] = (short)f2bf(a.z); v[3] = (short)f2bf(a.w);
  v[4] = (short)f2bf(b.x); v[5] = (short)f2bf(b.y);
  v[6] = (short)f2bf(b.z); v[7] = (short)f2bf(b.w);
  return v;
}

// ---------------- K1: h = x @ w1^T + b1 (bf16 MFMA, BM=32 BK=64, 512 threads) --------
// B staged from fp32 w1 inline (reg->cvt->LDS, swizzled) — k_prep eliminated.
// emits xnb [n][128], xnbT [b][128][2048], nrm [n]   (h == xn * nrm, never stored)
__global__ __launch_bounds__(512) void k_gemm_h(const float* __restrict__ x,
                                                const float* __restrict__ w1,
                                                const float* __restrict__ b1,
                                                USH* __restrict__ xnb,
                                                USH* __restrict__ xnbT,
                                                float* __restrict__ nrm) {
  __shared__ __align__(16) USH As[2][32][64];   // 8 KB  (slot-swizzled)
  __shared__ __align__(16) USH Bs[2][128][64];  // 32 KB (slot-swizzled)
  __shared__ float norms[32][4];
  __shared__ __align__(16) USH T[128][40];      // 10 KB transpose buffer

  const int t = threadIdx.x;      // 0..511
  const int w = t >> 6, l = t & 63;
  const int wm = w & 1;           // M-half: 16 rows
  const int wn = w >> 1;          // N-quarter: 32 cols
  const int row0 = blockIdx.x * 32;
  const int b_ = row0 >> 11, nloc = row0 & (NN - 1);

  // A staging: threads 0..255 -> row t>>3, logical k-slot t&7 (8 elems); swizzled
  const int arow = (t & 255) >> 3, aseg = t & 7;
  const int aslot = aseg ^ (arow & 7);
  const size_t xbase = (size_t)(row0 + arow) * HH;
  // B staging: all 512 threads -> w1 row t>>2 (0..127), seg t&3 (two 8-elem slots)
  const int brow = t >> 2, bseg = t & 3;
  const size_t wbase = (size_t)brow * HH;

  f32x4 acc[2] = {};

  {  // prologue: buffer 0
#pragma unroll
    for (int g = 0; g < 2; ++g) {
      int kslot = bseg * 2 + g;
      float4 wa = *reinterpret_cast<const float4*>(&w1[wbase + kslot * 8]);
      float4 wb = *reinterpret_cast<const float4*>(&w1[wbase + kslot * 8 + 4]);
      *reinterpret_cast<short8v*>(&Bs[0][brow][(kslot ^ (brow & 7)) * 8]) = cvt8(wa, wb);
    }
    if (t < 256) {
      float4 xa = *reinterpret_cast<const float4*>(&x[xbase + aseg * 8]);
      float4 xb = *reinterpret_cast<const float4*>(&x[xbase + aseg * 8 + 4]);
      *reinterpret_cast<short8v*>(&As[0][arow][aslot * 8]) = cvt8(xa, xb);
    }
  }

  for (int kt = 0; kt < HH / 64; ++kt) {
    const int cur = kt & 1, nxt = cur ^ 1;
    __syncthreads();

    float4 xa, xb, wa0, wb0, wa1, wb1;
    const bool more = (kt < HH / 64 - 1);
    if (more) {
      const int k0n = (kt + 1) * 64;
      wa0 = *reinterpret_cast<const float4*>(&w1[wbase + k0n + (bseg * 2) * 8]);
      wb0 = *reinterpret_cast<const float4*>(&w1[wbase + k0n + (bseg * 2) * 8 + 4]);
      wa1 = *reinterpret_cast<const float4*>(&w1[wbase + k0n + (bseg * 2 + 1) * 8]);
      wb1 = *reinterpret_cast<const float4*>(&w1[wbase + k0n + (bseg * 2 + 1) * 8 + 4]);
      if (t < 256) {
        xa = *reinterpret_cast<const float4*>(&x[xbase + k0n + aseg * 8]);
        xb = *reinterpret_cast<const float4*>(&x[xbase + k0n + aseg * 8 + 4]);
      }
    }

    const int ar = wm * 16 + (l & 15);
#pragma unroll
    for (int ks = 0; ks < 2; ++ks) {
      short8v a = *reinterpret_cast<const short8v*>(
          &As[cur][ar][((ks * 4 + (l >> 4)) ^ (ar & 7)) * 8]);
#pragma unroll
      for (int ni = 0; ni < 2; ++ni) {
        int br = wn * 32 + ni * 16 + (l & 15);
        short8v b = *reinterpret_cast<const short8v*>(
            &Bs[cur][br][((ks * 4 + (l >> 4)) ^ (br & 7)) * 8]);
        acc[ni] = __builtin_amdgcn_mfma_f32_16x16x32_bf16(a, b, acc[ni], 0, 0, 0);
      }
    }

    if (more) {
      *reinterpret_cast<short8v*>(&Bs[nxt][brow][((bseg * 2) ^ (brow & 7)) * 8])     = cvt8(wa0, wb0);
      *reinterpret_cast<short8v*>(&Bs[nxt][brow][((bseg * 2 + 1) ^ (brow & 7)) * 8]) = cvt8(wa1, wb1);
      if (t < 256)
        *reinterpret_cast<short8v*>(&As[nxt][arow][aslot * 8]) = cvt8(xa, xb);
    }
  }

  // epilogue: bias, row-norm, write xnb + xnbT + nrm
  float bv[2];
#pragma unroll
  for (int ni = 0; ni < 2; ++ni) bv[ni] = b1[wn * 32 + ni * 16 + (l & 15)];
#pragma unroll
  for (int ni = 0; ni < 2; ++ni)
#pragma unroll
    for (int r = 0; r < 4; ++r) acc[ni][r] += bv[ni];

#pragma unroll
  for (int r = 0; r < 4; ++r) {
    float s = 0.f;
#pragma unroll
    for (int ni = 0; ni < 2; ++ni) { float v = acc[ni][r]; s += v * v; }
#pragma unroll
    for (int m = 1; m < 16; m <<= 1) s += __shfl_xor(s, m, 64);
    if ((l & 15) == 0) norms[wm * 16 + (l >> 4) * 4 + r][wn] = s;
  }
  __syncthreads();

#pragma unroll
  for (int r = 0; r < 4; ++r) {
    int row = wm * 16 + (l >> 4) * 4 + r;
    float tot = norms[row][0] + norms[row][1] + norms[row][2] + norms[row][3];
    float ncl = fmaxf(sqrtf(tot), 1e-8f);
    float inv = 1.0f / ncl;
    if (wn == 0 && (l & 15) == 0) nrm[row0 + row] = ncl;
    size_t gbase = (size_t)(row0 + row) * D1;
#pragma unroll
    for (int ni = 0; ni < 2; ++ni) {
      int col = wn * 32 + ni * 16 + (l & 15);
      USH xv = f2bf(acc[ni][r] * inv);
      xnb[gbase + col] = xv;
      T[col][row] = xv;
    }
  }
  __syncthreads();
  {
    int d = t >> 2, seg = t & 3;
    size_t g = ((size_t)b_ * D1 + d) * NN + nloc + seg * 8;
    *reinterpret_cast<short8v*>(&xnbT[g]) =
        *reinterpret_cast<const short8v*>(&T[d][seg * 8]);
  }
}

// ---------------- K2: S1 partials (bf16 out) = xnT(chunk) @ (diag(nrm) xn)(chunk) ------
__global__ __launch_bounds__(256) void k_s1(const USH* __restrict__ xnbT,
                                            const float* __restrict__ nrm,
                                            USH* __restrict__ P1) {
  __shared__ __align__(16) short TA[128][72];   // 18.4 KB
  __shared__ __align__(16) short TB[128][72];
  const int t = threadIdx.x;
  const int ch = blockIdx.x, b = blockIdx.y;
  const int n0 = ch * ROWS_PER_CH;
  {
    const int r0 = t >> 3;          // 0..31
    const int c8 = (t & 7) * 8;     // 0..56
    float4 nva = *reinterpret_cast<const float4*>(&nrm[(size_t)b * NN + n0 + c8]);
    float4 nvb = *reinterpret_cast<const float4*>(&nrm[(size_t)b * NN + n0 + c8 + 4]);
    float nv[8] = {nva.x, nva.y, nva.z, nva.w, nvb.x, nvb.y, nvb.z, nvb.w};
#pragma unroll
    for (int p = 0; p < 4; ++p) {
      int row = p * 32 + r0;
      short8v v = *reinterpret_cast<const short8v*>(&xnbT[((size_t)b * D1 + row) * NN + n0 + c8]);
      *reinterpret_cast<short8v*>(&TA[row][c8]) = v;
      short8v hv;
#pragma unroll
      for (int j = 0; j < 8; ++j) hv[j] = (short)f2bf(bf2f((USH)v[j]) * nv[j]);
      *reinterpret_cast<short8v*>(&TB[row][c8]) = hv;
    }
  }
  __syncthreads();
  const int w = t >> 6, l = t & 63;
  const int wm = w & 1, wn = w >> 1;
  f32x4 acc[4][4] = {};
#pragma unroll
  for (int ks = 0; ks < 2; ++ks) {
    short8v a[4], bb[4];
#pragma unroll
    for (int fi = 0; fi < 4; ++fi)
      a[fi] = *reinterpret_cast<const short8v*>(&TA[wm * 64 + fi * 16 + (l & 15)][ks * 32 + (l >> 4) * 8]);
#pragma unroll
    for (int fj = 0; fj < 4; ++fj)
      bb[fj] = *reinterpret_cast<const short8v*>(&TB[wn * 64 + fj * 16 + (l & 15)][ks * 32 + (l >> 4) * 8]);
#pragma unroll
    for (int fi = 0; fi < 4; ++fi)
#pragma unroll
      for (int fj = 0; fj < 4; ++fj)
        acc[fi][fj] = __builtin_amdgcn_mfma_f32_16x16x32_bf16(a[fi], bb[fj], acc[fi][fj], 0, 0, 0);
  }
  USH* P = P1 + ((size_t)b * NCH + ch) * (D1 * D1);
#pragma unroll
  for (int fi = 0; fi < 4; ++fi)
#pragma unroll
    for (int fj = 0; fj < 4; ++fj)
#pragma unroll
      for (int r = 0; r < 4; ++r) {
        int row = wm * 64 + fi * 16 + (l >> 4) * 4 + r;
        int col = wn * 64 + fj * 16 + (l & 15);
        P[(size_t)row * D1 + col] = f2bf(acc[fi][fj][r]);
      }
}

// ---------------- K3: fused reduce(P1 bf16) + M1T = (S1@c1_lw^T/2047)^T (bf16) ---------
__global__ __launch_bounds__(256) void k_m1_fused(const USH* __restrict__ P1,
                                                  const float* __restrict__ c1_lw,
                                                  USH* __restrict__ M1T) {
  __shared__ float s_s[8][128];     // 4 KB
  __shared__ float lw_s[64][132];   // 33.8 KB
  const int t = threadIdx.x;
  const int dchunk = blockIdx.x;    // rows dchunk*8 .. +7
  const int b = blockIdx.y;
  const float inv = 1.0f / 2047.0f;

#pragma unroll
  for (int q = 0; q < 8; ++q) {
    int idx4 = q * 256 + t;
    int o = idx4 >> 5, e4 = idx4 & 31;
    float4 v = *reinterpret_cast<const float4*>(&c1_lw[o * 128 + e4 * 4]);
    *reinterpret_cast<float4*>(&lw_s[o][e4 * 4]) = v;
  }
  const USH* Pb = P1 + (size_t)b * NCH * (D1 * D1) + (size_t)(dchunk * 8) * D1;
  {
    int r = t >> 5, c4 = (t & 31) * 4;
    float4 s = make_float4(0.f, 0.f, 0.f, 0.f);
#pragma unroll
    for (int c = 0; c < NCH; ++c) {
      ushort4 v = *reinterpret_cast<const ushort4*>(&Pb[(size_t)c * (D1 * D1) + r * D1 + c4]);
      s.x += bf2f(v.x); s.y += bf2f(v.y); s.z += bf2f(v.z); s.w += bf2f(v.w);
    }
    *reinterpret_cast<float4*>(&s_s[r][c4]) = s;
  }
  __syncthreads();

  const int row = t >> 5;           // 0..7
  const int ox = t & 31;            // o and o+32
  float a0 = 0.f, a1 = 0.f;
  for (int e4 = 0; e4 < 32; ++e4) {
    float4 lw0 = *reinterpret_cast<const float4*>(&lw_s[ox][e4 * 4]);
    float4 lw1 = *reinterpret_cast<const float4*>(&lw_s[ox + 32][e4 * 4]);
    float4 sv = *reinterpret_cast<const float4*>(&s_s[row][e4 * 4]);
    a0 += sv.x * lw0.x + sv.y * lw0.y + sv.z * lw0.z + sv.w * lw0.w;
    a1 += sv.x * lw1.x + sv.y * lw1.y + sv.z * lw1.z + sv.w * lw1.w;
  }
  int d = dchunk * 8 + row;
  M1T[((size_t)b * D2 + ox) * D1 + d]      = f2bf(a0 * inv);
  M1T[((size_t)b * D2 + ox + 32) * D1 + d] = f2bf(a1 * inv);
}

// ---------------- K4: h1 = relu([xn | nrm*xn] @ [M1T|R1T]^T + c1_lb) (K=256 MFMA) ------
// R1T computed inline from c1_rw/c1_lw; r2 computed inline from c2_rw/c2_lw.
__global__ __launch_bounds__(256) void k_h1(const USH* __restrict__ xnb,
                                            const float* __restrict__ nrm,
                                            const USH* __restrict__ M1T,
                                            const float* __restrict__ c1_rw,
                                            const float* __restrict__ c1_lw,
                                            const float* __restrict__ c1_lb,
                                            const float* __restrict__ c2_lw,
                                            const float* __restrict__ c2_rw,
                                            float* __restrict__ w2,
                                            float* __restrict__ t2v) {
  __shared__ __align__(16) short TA[64][280];
  __shared__ __align__(16) short TB[64][280];
  __shared__ float ws2[64][2], ts2[64][2];
  const int t = threadIdx.x;
  const int row0 = blockIdx.x * 64;
  const int b = row0 >> 11;
  const float inv2047 = 1.0f / 2047.0f;
  {
    const int row = t >> 2, seg = t & 3;
    const float nr = nrm[row0 + row];
#pragma unroll
    for (int j = 0; j < 4; ++j) {
      int e = seg * 32 + j * 8;
      short8v v = *reinterpret_cast<const short8v*>(&xnb[(size_t)(row0 + row) * D1 + e]);
      *reinterpret_cast<short8v*>(&TA[row][e]) = v;
      short8v sv;
#pragma unroll
      for (int jj = 0; jj < 8; ++jj) sv[jj] = (short)f2bf(bf2f((USH)v[jj]) * nr);
      *reinterpret_cast<short8v*>(&TA[row][128 + e]) = sv;
      *reinterpret_cast<short8v*>(&TB[row][e]) =
          *reinterpret_cast<const short8v*>(&M1T[((size_t)b * D2 + row) * D1 + e]);
      // R1T inline: c1_rw[row][e..] - c1_lw[row][e..]/2047  (both [64][128] row-major)
      float4 ra = *reinterpret_cast<const float4*>(&c1_rw[row * D1 + e]);
      float4 rb = *reinterpret_cast<const float4*>(&c1_rw[row * D1 + e + 4]);
      float4 la = *reinterpret_cast<const float4*>(&c1_lw[row * D1 + e]);
      float4 lb4 = *reinterpret_cast<const float4*>(&c1_lw[row * D1 + e + 4]);
      float4 qa = make_float4(ra.x - la.x * inv2047, ra.y - la.y * inv2047,
                              ra.z - la.z * inv2047, ra.w - la.w * inv2047);
      float4 qb = make_float4(rb.x - lb4.x * inv2047, rb.y - lb4.y * inv2047,
                              rb.z - lb4.z * inv2047, rb.w - lb4.w * inv2047);
      *reinterpret_cast<short8v*>(&TB[row][128 + e]) = cvt8(qa, qb);
    }
  }
  __syncthreads();
  const int w = t >> 6, l = t & 63;
  const int wm = w & 1, wn = w >> 1;
  f32x4 acc[2][2] = {};
#pragma unroll
  for (int ks = 0; ks < 8; ++ks) {
    short8v a[2], bb[2];
#pragma unroll
    for (int i = 0; i < 2; ++i)
      a[i] = *reinterpret_cast<const short8v*>(&TA[wm * 32 + i * 16 + (l & 15)][ks * 32 + (l >> 4) * 8]);
#pragma unroll
    for (int j = 0; j < 2; ++j)
      bb[j] = *reinterpret_cast<const short8v*>(&TB[wn * 32 + j * 16 + (l & 15)][ks * 32 + (l >> 4) * 8]);
#pragma unroll
    for (int i = 0; i < 2; ++i)
#pragma unroll
      for (int j = 0; j < 2; ++j)
        acc[i][j] = __builtin_amdgcn_mfma_f32_16x16x32_bf16(a[i], bb[j], acc[i][j], 0, 0, 0);
  }
  // per-row reductions against c2_lw and inline r2
  float cw[2], rv[2], lb[2];
#pragma unroll
  for (int j = 0; j < 2; ++j) {
    int col = wn * 32 + j * 16 + (l & 15);
    cw[j] = c2_lw[col];
    rv[j] = c2_rw[col] - c2_lw[col] * inv2047;
    lb[j] = c1_lb[col];
  }
#pragma unroll
  for (int i = 0; i < 2; ++i)
#pragma unroll
    for (int r = 0; r < 4; ++r) {
      float wp = 0.f, tp = 0.f;
#pragma unroll
      for (int j = 0; j < 2; ++j) {
        float val = fmaxf(acc[i][j][r] + lb[j], 0.0f);
        wp += val * cw[j];
        tp += val * rv[j];
      }
#pragma unroll
      for (int m = 1; m < 16; m <<= 1) {
        wp += __shfl_xor(wp, m, 64);
        tp += __shfl_xor(tp, m, 64);
      }
      if ((l & 15) == 0) {
        int rowL = wm * 32 + i * 16 + (l >> 4) * 4 + r;
        ws2[rowL][wn] = wp;
        ts2[rowL][wn] = tp;
      }
    }
  __syncthreads();
  if (t < 64) {
    w2[row0 + t]  = ws2[t][0] + ws2[t][1];
    t2v[row0 + t] = ts2[t][0] + ts2[t][1];
  }
}

// ---------------- K5: m2[b][d] = (sum_n xnbT[b][d][n] * w2[b][n]) / 2047 (GEMV) --------
__global__ __launch_bounds__(256) void k_m2(const USH* __restrict__ xnbT,
                                            const float* __restrict__ w2,
                                            float* __restrict__ m2f) {
  const int t = threadIdx.x;
  const int w = t >> 6, l = t & 63;
  const int b = blockIdx.y;
  const int d = blockIdx.x * 4 + w;
  const USH* xr = xnbT + ((size_t)b * D1 + d) * NN;
  const float* wr = w2 + (size_t)b * NN;
  float s = 0.f;
#pragma unroll
  for (int pass = 0; pass < 4; ++pass) {
    int n0 = pass * 512 + l * 8;
    short8v xv = *reinterpret_cast<const short8v*>(&xr[n0]);
    float4 wa = *reinterpret_cast<const float4*>(&wr[n0]);
    float4 wb = *reinterpret_cast<const float4*>(&wr[n0 + 4]);
    s += bf2f((USH)xv[0]) * wa.x + bf2f((USH)xv[1]) * wa.y
       + bf2f((USH)xv[2]) * wa.z + bf2f((USH)xv[3]) * wa.w
       + bf2f((USH)xv[4]) * wb.x + bf2f((USH)xv[5]) * wb.y
       + bf2f((USH)xv[6]) * wb.z + bf2f((USH)xv[7]) * wb.w;
  }
#pragma unroll
  for (int m = 1; m < 64; m <<= 1) s += __shfl_xor(s, m, 64);
  if (l == 0) m2f[b * D1 + d] = s * (1.0f / 2047.0f);
}

// ---------------- K6: out = sigmoid(xnb.m2 + t2 + c2_lb) * mask ----------------
__global__ __launch_bounds__(256) void k_out(const USH* __restrict__ xnb,
                                             const float* __restrict__ m2f,
                                             const float* __restrict__ t2v,
                                             const float* __restrict__ c2_lb,
                                             const float* __restrict__ mask,
                                             float* __restrict__ out) {
  int row = blockIdx.x * 4 + (threadIdx.x >> 6);
  int lane = threadIdx.x & 63;
  int b = row >> 11;
  float s = bf2f(xnb[(size_t)row * D1 + lane]) * m2f[b * D1 + lane]
          + bf2f(xnb[(size_t)row * D1 + 64 + lane]) * m2f[b * D1 + 64 + lane];
#pragma unroll
  for (int m = 1; m < 64; m <<= 1) s += __shfl_xor(s, m, 64);
  if (lane == 0) {
    float v = s + t2v[row] + c2_lb[0];
    out[row] = (1.0f / (1.0f + expf(-v))) * mask[row];
  }
}

extern "C" void kernel_launch(void* const* d_in, const int* in_sizes, int n_in,
                              void* d_out, int out_size, void* d_ws, size_t ws_size,
                              hipStream_t stream) {
  const float* x      = (const float*)d_in[0];
  const float* mask   = (const float*)d_in[1];
  const float* w1     = (const float*)d_in[2];
  const float* b1     = (const float*)d_in[3];
  const float* c1_lw  = (const float*)d_in[4];
  const float* c1_lb  = (const float*)d_in[5];
  const float* c1_rw  = (const float*)d_in[6];
  const float* c2_lw  = (const float*)d_in[7];
  const float* c2_lb  = (const float*)d_in[8];
  const float* c2_rw  = (const float*)d_in[9];
  float* ws  = (float*)d_ws;
  USH* xnb   = (USH*)(ws + OFF_XNB);
  USH* xnbT  = (USH*)(ws + OFF_XNBT);
  float* nrm = ws + OFF_NRM;
  float* w2  = ws + OFF_W2;
  float* t2v = ws + OFF_T2V;
  USH* P1    = (USH*)(ws + OFF_P1);
  USH* M1T   = (USH*)(ws + OFF_M1T);
  float* m2f = ws + OFF_M2F;
  float* out = (float*)d_out;

  k_gemm_h<<<dim3(BN / 32), dim3(512), 0, stream>>>(x, w1, b1, xnb, xnbT, nrm);
  k_s1<<<dim3(NCH, BB), dim3(256), 0, stream>>>(xnbT, nrm, P1);
  k_m1_fused<<<dim3(16, BB), dim3(256), 0, stream>>>(P1, c1_lw, M1T);
  k_h1<<<dim3(BN / 64), dim3(256), 0, stream>>>(xnb, nrm, M1T, c1_rw, c1_lw, c1_lb, c2_lw, c2_rw, w2, t2v);
  k_m2<<<dim3(32, BB), dim3(256), 0, stream>>>(xnbT, w2, m2f);
  k_out<<<dim3(BN / 4), dim3(256), 0, stream>>>(xnb, m2f, t2v, c2_lb, mask, out);
}

// Round 13
// 45.271 us; speedup vs baseline: 1.0413x; 1.0413x over previous
//
#include <hip/hip_runtime.h>
#include <hip/hip_bf16.h>
#include <math.h>

#define BB 8
#define NN 2048
#define HH 768
#define D1 128
#define D2 64
#define BN (BB*NN)            // 16384 rows total
#define NCH 32                // split-n chunks for S1 partial reduction (64 rows each)
#define ROWS_PER_CH (NN/NCH)  // 64

// workspace offsets (floats)
#define OFF_XNB   0u          // bf16 [BN][128]
#define OFF_XNBT  1048576u    // bf16 [8][128][2048]
#define OFF_NRM   2097152u    // f32  [BN]
#define OFF_W2    2113536u    // f32  [BN]   (h1 . c2_lw per row)
#define OFF_T2V   2129920u    // f32  [BN]   (h1 . r2 per row)
#define OFF_P1    2146304u    // bf16 [8][32][128][128] = 8 MB  (w1b bf16 aliases here pre-s1)
#define OFF_M1T   4243456u    // bf16 [8][64][128]
#define OFF_R1T   4276224u    // bf16 [64][128]
#define OFF_M2F   4280320u    // f32 [8][128]
#define OFF_R2F   4281344u    // f32 [64]

typedef __attribute__((ext_vector_type(8))) short short8v;
typedef __attribute__((ext_vector_type(4))) float f32x4;
typedef unsigned short USH;

__device__ __forceinline__ USH f2bf(float f) {
  unsigned int u = __builtin_bit_cast(unsigned int, f);
  u = (u + 0x7fffu + ((u >> 16) & 1u)) >> 16;
  return (USH)u;
}
__device__ __forceinline__ float bf2f(USH u) {
  return __builtin_bit_cast(float, ((unsigned int)u) << 16);
}

#define GLDS16(gp, lp)                                                        \
  __builtin_amdgcn_global_load_lds((const __attribute__((address_space(1))) void*)(gp), \
                                   (__attribute__((address_space(3))) void*)(lp), 16, 0, 0)

// ---------------- K0: prep — w1->bf16, R1T, r2 ----------------
__global__ __launch_bounds__(256) void k_prep(const float* __restrict__ w1,
                                              const float* __restrict__ c1_lw,
                                              const float* __restrict__ c1_rw,
                                              const float* __restrict__ c2_lw,
                                              const float* __restrict__ c2_rw,
                                              USH* __restrict__ w1b,
                                              USH* __restrict__ R1T,
                                              float* __restrict__ r2f) {
  const int bid = blockIdx.x, t = threadIdx.x;
  const float inv = 1.0f / 2047.0f;
  if (bid < 96) {
    int i = (bid * 256 + t) * 4;
    float4 v = *reinterpret_cast<const float4*>(&w1[i]);
    ushort4 o;
    o.x = f2bf(v.x); o.y = f2bf(v.y); o.z = f2bf(v.z); o.w = f2bf(v.w);
    *reinterpret_cast<ushort4*>(&w1b[i]) = o;
  } else if (bid < 98) {
    int base = (bid - 96) * 4096 + t * 16;
#pragma unroll
    for (int k = 0; k < 16; ++k) {
      int i = base + k;
      R1T[i] = f2bf(c1_rw[i] - c1_lw[i] * inv);
    }
  } else {
    if (t < D2) r2f[t] = c2_rw[t] - c2_lw[t] * inv;
  }
}

// ---------------- K1: h = x @ w1^T + b1 (bf16 MFMA, BM=32 BK=64, 512 threads) --------
__global__ __launch_bounds__(512) void k_gemm_h(const float* __restrict__ x,
                                                const USH* __restrict__ w1b,
                                                const float* __restrict__ b1,
                                                USH* __restrict__ xnb,
                                                USH* __restrict__ xnbT,
                                                float* __restrict__ nrm) {
  __shared__ __align__(16) USH As[2][32][64];   // 8 KB  (slot-swizzled)
  __shared__ __align__(16) USH Bs[2][128][64];  // 32 KB (slot-swizzled)
  __shared__ float norms[32][4];
  __shared__ __align__(16) USH T[128][40];      // 10 KB transpose buffer

  const int t = threadIdx.x;      // 0..511
  const int w = t >> 6, l = t & 63;
  const int wm = w & 1;           // M-half: 16 rows
  const int wn = w >> 1;          // N-quarter: 32 cols
  const int row0 = blockIdx.x * 32;
  const int b_ = row0 >> 11, nloc = row0 & (NN - 1);

  const int arow = (t & 255) >> 3, aseg = t & 7;
  const int aslot = aseg ^ (arow & 7);
  const size_t xbase = (size_t)(row0 + arow) * HH;
  const int brow_l = w * 16 + (l >> 3);

  f32x4 acc[2] = {};

  {  // prologue: buffer 0
#pragma unroll
    for (int q = 0; q < 2; ++q) {
      int brow = brow_l + q * 8;
      int gslot = (l & 7) ^ (brow & 7);
      GLDS16(w1b + (size_t)brow * HH + gslot * 8, &Bs[0][w * 16 + q * 8][0]);
    }
    if (t < 256) {
      float4 xa = *reinterpret_cast<const float4*>(&x[xbase + aseg * 8]);
      float4 xb = *reinterpret_cast<const float4*>(&x[xbase + aseg * 8 + 4]);
      short8v v;
      v[0] = (short)f2bf(xa.x); v[1] = (short)f2bf(xa.y);
      v[2] = (short)f2bf(xa.z); v[3] = (short)f2bf(xa.w);
      v[4] = (short)f2bf(xb.x); v[5] = (short)f2bf(xb.y);
      v[6] = (short)f2bf(xb.z); v[7] = (short)f2bf(xb.w);
      *reinterpret_cast<short8v*>(&As[0][arow][aslot * 8]) = v;
    }
  }

  for (int kt = 0; kt < HH / 64; ++kt) {
    const int cur = kt & 1, nxt = cur ^ 1;
    __syncthreads();

    float4 xa, xb;
    const bool doA = (t < 256) && (kt < HH / 64 - 1);
    if (kt < HH / 64 - 1) {
      const int k0n = (kt + 1) * 64;
#pragma unroll
      for (int q = 0; q < 2; ++q) {
        int brow = brow_l + q * 8;
        int gslot = (l & 7) ^ (brow & 7);
        GLDS16(w1b + (size_t)brow * HH + k0n + gslot * 8, &Bs[nxt][w * 16 + q * 8][0]);
      }
      if (t < 256) {
        xa = *reinterpret_cast<const float4*>(&x[xbase + k0n + aseg * 8]);
        xb = *reinterpret_cast<const float4*>(&x[xbase + k0n + aseg * 8 + 4]);
      }
    }

    const int ar = wm * 16 + (l & 15);
#pragma unroll
    for (int ks = 0; ks < 2; ++ks) {
      short8v a = *reinterpret_cast<const short8v*>(
          &As[cur][ar][((ks * 4 + (l >> 4)) ^ (ar & 7)) * 8]);
#pragma unroll
      for (int ni = 0; ni < 2; ++ni) {
        int br = wn * 32 + ni * 16 + (l & 15);
        short8v b = *reinterpret_cast<const short8v*>(
            &Bs[cur][br][((ks * 4 + (l >> 4)) ^ (br & 7)) * 8]);
        acc[ni] = __builtin_amdgcn_mfma_f32_16x16x32_bf16(a, b, acc[ni], 0, 0, 0);
      }
    }

    if (doA) {
      short8v v;
      v[0] = (short)f2bf(xa.x); v[1] = (short)f2bf(xa.y);
      v[2] = (short)f2bf(xa.z); v[3] = (short)f2bf(xa.w);
      v[4] = (short)f2bf(xb.x); v[5] = (short)f2bf(xb.y);
      v[6] = (short)f2bf(xb.z); v[7] = (short)f2bf(xb.w);
      *reinterpret_cast<short8v*>(&As[nxt][arow][aslot * 8]) = v;
    }
  }

  // epilogue: bias, row-norm, write xnb + xnbT + nrm
  float bv[2];
#pragma unroll
  for (int ni = 0; ni < 2; ++ni) bv[ni] = b1[wn * 32 + ni * 16 + (l & 15)];
#pragma unroll
  for (int ni = 0; ni < 2; ++ni)
#pragma unroll
    for (int r = 0; r < 4; ++r) acc[ni][r] += bv[ni];

#pragma unroll
  for (int r = 0; r < 4; ++r) {
    float s = 0.f;
#pragma unroll
    for (int ni = 0; ni < 2; ++ni) { float v = acc[ni][r]; s += v * v; }
#pragma unroll
    for (int m = 1; m < 16; m <<= 1) s += __shfl_xor(s, m, 64);
    if ((l & 15) == 0) norms[wm * 16 + (l >> 4) * 4 + r][wn] = s;
  }
  __syncthreads();

#pragma unroll
  for (int r = 0; r < 4; ++r) {
    int row = wm * 16 + (l >> 4) * 4 + r;
    float tot = norms[row][0] + norms[row][1] + norms[row][2] + norms[row][3];
    float ncl = fmaxf(sqrtf(tot), 1e-8f);
    float inv = 1.0f / ncl;
    if (wn == 0 && (l & 15) == 0) nrm[row0 + row] = ncl;
    size_t gbase = (size_t)(row0 + row) * D1;
#pragma unroll
    for (int ni = 0; ni < 2; ++ni) {
      int col = wn * 32 + ni * 16 + (l & 15);
      USH xv = f2bf(acc[ni][r] * inv);
      xnb[gbase + col] = xv;
      T[col][row] = xv;
    }
  }
  __syncthreads();
  {
    int d = t >> 2, seg = t & 3;
    size_t g = ((size_t)b_ * D1 + d) * NN + nloc + seg * 8;
    *reinterpret_cast<short8v*>(&xnbT[g]) =
        *reinterpret_cast<const short8v*>(&T[d][seg * 8]);
  }
}

// ---------------- K2: S1 partials (bf16 out) = xnT(chunk) @ (diag(nrm) xn)(chunk) ------
// grid (32 ch, 8 b) = 256 blocks (full CU coverage); 64-row chunks, K=64.
__global__ __launch_bounds__(256) void k_s1(const USH* __restrict__ xnbT,
                                            const float* __restrict__ nrm,
                                            USH* __restrict__ P1) {
  __shared__ __align__(16) short TA[128][72];   // 18.4 KB
  __shared__ __align__(16) short TB[128][72];
  const int t = threadIdx.x;
  const int ch = blockIdx.x, b = blockIdx.y;
  const int n0 = ch * ROWS_PER_CH;
  {
    const int r0 = t >> 3;          // 0..31
    const int c8 = (t & 7) * 8;     // 0..56
    float4 nva = *reinterpret_cast<const float4*>(&nrm[(size_t)b * NN + n0 + c8]);
    float4 nvb = *reinterpret_cast<const float4*>(&nrm[(size_t)b * NN + n0 + c8 + 4]);
    float nv[8] = {nva.x, nva.y, nva.z, nva.w, nvb.x, nvb.y, nvb.z, nvb.w};
#pragma unroll
    for (int p = 0; p < 4; ++p) {
      int row = p * 32 + r0;
      short8v v = *reinterpret_cast<const short8v*>(&xnbT[((size_t)b * D1 + row) * NN + n0 + c8]);
      *reinterpret_cast<short8v*>(&TA[row][c8]) = v;
      short8v hv;
#pragma unroll
      for (int j = 0; j < 8; ++j) hv[j] = (short)f2bf(bf2f((USH)v[j]) * nv[j]);
      *reinterpret_cast<short8v*>(&TB[row][c8]) = hv;
    }
  }
  __syncthreads();
  const int w = t >> 6, l = t & 63;
  const int wm = w & 1, wn = w >> 1;
  f32x4 acc[4][4] = {};
#pragma unroll
  for (int ks = 0; ks < 2; ++ks) {
    short8v a[4], bb[4];
#pragma unroll
    for (int fi = 0; fi < 4; ++fi)
      a[fi] = *reinterpret_cast<const short8v*>(&TA[wm * 64 + fi * 16 + (l & 15)][ks * 32 + (l >> 4) * 8]);
#pragma unroll
    for (int fj = 0; fj < 4; ++fj)
      bb[fj] = *reinterpret_cast<const short8v*>(&TB[wn * 64 + fj * 16 + (l & 15)][ks * 32 + (l >> 4) * 8]);
#pragma unroll
    for (int fi = 0; fi < 4; ++fi)
#pragma unroll
      for (int fj = 0; fj < 4; ++fj)
        acc[fi][fj] = __builtin_amdgcn_mfma_f32_16x16x32_bf16(a[fi], bb[fj], acc[fi][fj], 0, 0, 0);
  }
  USH* P = P1 + ((size_t)b * NCH + ch) * (D1 * D1);
#pragma unroll
  for (int fi = 0; fi < 4; ++fi)
#pragma unroll
    for (int fj = 0; fj < 4; ++fj)
#pragma unroll
      for (int r = 0; r < 4; ++r) {
        int row = wm * 64 + fi * 16 + (l >> 4) * 4 + r;
        int col = wn * 64 + fj * 16 + (l & 15);
        P[(size_t)row * D1 + col] = f2bf(acc[fi][fj][r]);
      }
}

// ---------------- K3: fused reduce(P1 bf16) + M1T = (S1@c1_lw^T/2047)^T (bf16) ---------
// grid (16 d-chunks of 8 rows, 8 b), 256 threads
__global__ __launch_bounds__(256) void k_m1_fused(const USH* __restrict__ P1,
                                                  const float* __restrict__ c1_lw,
                                                  USH* __restrict__ M1T) {
  __shared__ float s_s[8][128];     // 4 KB
  __shared__ float lw_s[64][132];   // 33.8 KB
  const int t = threadIdx.x;
  const int dchunk = blockIdx.x;    // rows dchunk*8 .. +7
  const int b = blockIdx.y;
  const float inv = 1.0f / 2047.0f;

#pragma unroll
  for (int q = 0; q < 8; ++q) {
    int idx4 = q * 256 + t;
    int o = idx4 >> 5, e4 = idx4 & 31;
    float4 v = *reinterpret_cast<const float4*>(&c1_lw[o * 128 + e4 * 4]);
    *reinterpret_cast<float4*>(&lw_s[o][e4 * 4]) = v;
  }
  const USH* Pb = P1 + (size_t)b * NCH * (D1 * D1) + (size_t)(dchunk * 8) * D1;
  {
    int r = t >> 5, c4 = (t & 31) * 4;
    float4 s = make_float4(0.f, 0.f, 0.f, 0.f);
#pragma unroll
    for (int c = 0; c < NCH; ++c) {
      ushort4 v = *reinterpret_cast<const ushort4*>(&Pb[(size_t)c * (D1 * D1) + r * D1 + c4]);
      s.x += bf2f(v.x); s.y += bf2f(v.y); s.z += bf2f(v.z); s.w += bf2f(v.w);
    }
    *reinterpret_cast<float4*>(&s_s[r][c4]) = s;
  }
  __syncthreads();

  const int row = t >> 5;           // 0..7
  const int ox = t & 31;            // o and o+32
  float a0 = 0.f, a1 = 0.f;
  for (int e4 = 0; e4 < 32; ++e4) {
    float4 lw0 = *reinterpret_cast<const float4*>(&lw_s[ox][e4 * 4]);
    float4 lw1 = *reinterpret_cast<const float4*>(&lw_s[ox + 32][e4 * 4]);
    float4 sv = *reinterpret_cast<const float4*>(&s_s[row][e4 * 4]);
    a0 += sv.x * lw0.x + sv.y * lw0.y + sv.z * lw0.z + sv.w * lw0.w;
    a1 += sv.x * lw1.x + sv.y * lw1.y + sv.z * lw1.z + sv.w * lw1.w;
  }
  int d = dchunk * 8 + row;
  M1T[((size_t)b * D2 + ox) * D1 + d]      = f2bf(a0 * inv);
  M1T[((size_t)b * D2 + ox + 32) * D1 + d] = f2bf(a1 * inv);
}

// ---------------- K4: h1 = relu([xn | nrm*xn] @ [M1T|R1T]^T + c1_lb) (K=256 MFMA) ------
__global__ __launch_bounds__(256) void k_h1(const USH* __restrict__ xnb,
                                            const float* __restrict__ nrm,
                                            const USH* __restrict__ M1T,
                                            const USH* __restrict__ R1T,
                                            const float* __restrict__ c1_lb,
                                            const float* __restrict__ c2_lw,
                                            const float* __restrict__ r2f,
                                            float* __restrict__ w2,
                                            float* __restrict__ t2v) {
  __shared__ __align__(16) short TA[64][280];
  __shared__ __align__(16) short TB[64][280];
  __shared__ float ws2[64][2], ts2[64][2];
  const int t = threadIdx.x;
  const int row0 = blockIdx.x * 64;
  const int b = row0 >> 11;
  {
    const int row = t >> 2, seg = t & 3;
    const float nr = nrm[row0 + row];
#pragma unroll
    for (int j = 0; j < 4; ++j) {
      int e = seg * 32 + j * 8;
      short8v v = *reinterpret_cast<const short8v*>(&xnb[(size_t)(row0 + row) * D1 + e]);
      *reinterpret_cast<short8v*>(&TA[row][e]) = v;
      short8v sv;
#pragma unroll
      for (int jj = 0; jj < 8; ++jj) sv[jj] = (short)f2bf(bf2f((USH)v[jj]) * nr);
      *reinterpret_cast<short8v*>(&TA[row][128 + e]) = sv;
      *reinterpret_cast<short8v*>(&TB[row][e]) =
          *reinterpret_cast<const short8v*>(&M1T[((size_t)b * D2 + row) * D1 + e]);
      *reinterpret_cast<short8v*>(&TB[row][128 + e]) =
          *reinterpret_cast<const short8v*>(&R1T[(size_t)row * D1 + e]);
    }
  }
  __syncthreads();
  const int w = t >> 6, l = t & 63;
  const int wm = w & 1, wn = w >> 1;
  f32x4 acc[2][2] = {};
#pragma unroll
  for (int ks = 0; ks < 8; ++ks) {
    short8v a[2], bb[2];
#pragma unroll
    for (int i = 0; i < 2; ++i)
      a[i] = *reinterpret_cast<const short8v*>(&TA[wm * 32 + i * 16 + (l & 15)][ks * 32 + (l >> 4) * 8]);
#pragma unroll
    for (int j = 0; j < 2; ++j)
      bb[j] = *reinterpret_cast<const short8v*>(&TB[wn * 32 + j * 16 + (l & 15)][ks * 32 + (l >> 4) * 8]);
#pragma unroll
    for (int i = 0; i < 2; ++i)
#pragma unroll
      for (int j = 0; j < 2; ++j)
        acc[i][j] = __builtin_amdgcn_mfma_f32_16x16x32_bf16(a[i], bb[j], acc[i][j], 0, 0, 0);
  }
  // per-row reductions against c2_lw and r2
  float cw[2], rv[2], lb[2];
#pragma unroll
  for (int j = 0; j < 2; ++j) {
    int col = wn * 32 + j * 16 + (l & 15);
    cw[j] = c2_lw[col]; rv[j] = r2f[col]; lb[j] = c1_lb[col];
  }
#pragma unroll
  for (int i = 0; i < 2; ++i)
#pragma unroll
    for (int r = 0; r < 4; ++r) {
      float wp = 0.f, tp = 0.f;
#pragma unroll
      for (int j = 0; j < 2; ++j) {
        float val = fmaxf(acc[i][j][r] + lb[j], 0.0f);
        wp += val * cw[j];
        tp += val * rv[j];
      }
#pragma unroll
      for (int m = 1; m < 16; m <<= 1) {
        wp += __shfl_xor(wp, m, 64);
        tp += __shfl_xor(tp, m, 64);
      }
      if ((l & 15) == 0) {
        int rowL = wm * 32 + i * 16 + (l >> 4) * 4 + r;
        ws2[rowL][wn] = wp;
        ts2[rowL][wn] = tp;
      }
    }
  __syncthreads();
  if (t < 64) {
    w2[row0 + t]  = ws2[t][0] + ws2[t][1];
    t2v[row0 + t] = ts2[t][0] + ts2[t][1];
  }
}

// ---------------- K5: m2[b][d] = (sum_n xnbT[b][d][n] * w2[b][n]) / 2047 (GEMV) --------
__global__ __launch_bounds__(256) void k_m2(const USH* __restrict__ xnbT,
                                            const float* __restrict__ w2,
                                            float* __restrict__ m2f) {
  const int t = threadIdx.x;
  const int w = t >> 6, l = t & 63;
  const int b = blockIdx.y;
  const int d = blockIdx.x * 4 + w;
  const USH* xr = xnbT + ((size_t)b * D1 + d) * NN;
  const float* wr = w2 + (size_t)b * NN;
  float s = 0.f;
#pragma unroll
  for (int pass = 0; pass < 4; ++pass) {
    int n0 = pass * 512 + l * 8;
    short8v xv = *reinterpret_cast<const short8v*>(&xr[n0]);
    float4 wa = *reinterpret_cast<const float4*>(&wr[n0]);
    float4 wb = *reinterpret_cast<const float4*>(&wr[n0 + 4]);
    s += bf2f((USH)xv[0]) * wa.x + bf2f((USH)xv[1]) * wa.y
       + bf2f((USH)xv[2]) * wa.z + bf2f((USH)xv[3]) * wa.w
       + bf2f((USH)xv[4]) * wb.x + bf2f((USH)xv[5]) * wb.y
       + bf2f((USH)xv[6]) * wb.z + bf2f((USH)xv[7]) * wb.w;
  }
#pragma unroll
  for (int m = 1; m < 64; m <<= 1) s += __shfl_xor(s, m, 64);
  if (l == 0) m2f[b * D1 + d] = s * (1.0f / 2047.0f);
}

// ---------------- K6: out = sigmoid(xnb.m2 + t2 + c2_lb) * mask ----------------
__global__ __launch_bounds__(256) void k_out(const USH* __restrict__ xnb,
                                             const float* __restrict__ m2f,
                                             const float* __restrict__ t2v,
                                             const float* __restrict__ c2_lb,
                                             const float* __restrict__ mask,
                                             float* __restrict__ out) {
  int row = blockIdx.x * 4 + (threadIdx.x >> 6);
  int lane = threadIdx.x & 63;
  int b = row >> 11;
  float s = bf2f(xnb[(size_t)row * D1 + lane]) * m2f[b * D1 + lane]
          + bf2f(xnb[(size_t)row * D1 + 64 + lane]) * m2f[b * D1 + 64 + lane];
#pragma unroll
  for (int m = 1; m < 64; m <<= 1) s += __shfl_xor(s, m, 64);
  if (lane == 0) {
    float v = s + t2v[row] + c2_lb[0];
    out[row] = (1.0f / (1.0f + expf(-v))) * mask[row];
  }
}

extern "C" void kernel_launch(void* const* d_in, const int* in_sizes, int n_in,
                              void* d_out, int out_size, void* d_ws, size_t ws_size,
                              hipStream_t stream) {
  const float* x      = (const float*)d_in[0];
  const float* mask   = (const float*)d_in[1];
  const float* w1     = (const float*)d_in[2];
  const float* b1     = (const float*)d_in[3];
  const float* c1_lw  = (const float*)d_in[4];
  const float* c1_lb  = (const float*)d_in[5];
  const float* c1_rw  = (const float*)d_in[6];
  const float* c2_lw  = (const float*)d_in[7];
  const float* c2_lb  = (const float*)d_in[8];
  const float* c2_rw  = (const float*)d_in[9];
  float* ws  = (float*)d_ws;
  USH* xnb   = (USH*)(ws + OFF_XNB);
  USH* xnbT  = (USH*)(ws + OFF_XNBT);
  float* nrm = ws + OFF_NRM;
  float* w2  = ws + OFF_W2;
  float* t2v = ws + OFF_T2V;
  USH* P1    = (USH*)(ws + OFF_P1);
  USH* M1T   = (USH*)(ws + OFF_M1T);
  USH* R1T   = (USH*)(ws + OFF_R1T);
  float* m2f = ws + OFF_M2F;
  float* r2f = ws + OFF_R2F;
  USH* w1b   = (USH*)(ws + OFF_P1);  // aliases P1 (P1 written only after gemm_h done)
  float* out = (float*)d_out;

  k_prep<<<dim3(99), dim3(256), 0, stream>>>(w1, c1_lw, c1_rw, c2_lw, c2_rw, w1b, R1T, r2f);
  k_gemm_h<<<dim3(BN / 32), dim3(512), 0, stream>>>(x, w1b, b1, xnb, xnbT, nrm);
  k_s1<<<dim3(NCH, BB), dim3(256), 0, stream>>>(xnbT, nrm, P1);
  k_m1_fused<<<dim3(16, BB), dim3(256), 0, stream>>>(P1, c1_lw, M1T);
  k_h1<<<dim3(BN / 64), dim3(256), 0, stream>>>(xnb, nrm, M1T, R1T, c1_lb, c2_lw, r2f, w2, t2v);
  k_m2<<<dim3(32, BB), dim3(256), 0, stream>>>(xnbT, w2, m2f);
  k_out<<<dim3(BN / 4), dim3(256), 0, stream>>>(xnb, m2f, t2v, c2_lb, mask, out);
}